// Round 1
// baseline (233.132 us; speedup 1.0000x reference)
//
#include <hip/hip_runtime.h>

// DFAProb: transposed-DFA fuzzy sum-product, semiring='prob'.
// Per row i (B = 2M rows, 8 states):
//   ab = a*b, anb = a*(1-b), na = 1-a
//   unnorm[ns] = s0[(ns-1)&7]*ab + s0[(ns-2)&7]*anb + s0[ns]*na
//   denom = sum(unnorm)  (detached -> forward only)
//   next  = clip(unnorm/denom, 1e-7, 1-1e-7)
//   outputs (concat flat): log(next) [B*8], next [B*8], next[:,7] [B]
// log_s0 input is UNUSED by the reference -> never read (saves 64 MB).
// Memory-bound: ~216 MB total traffic -> ~34 us at 6.3 TB/s.

#define DFA_EPS 1e-7f

__global__ __launch_bounds__(256) void dfa_prob_kernel(
    const float* __restrict__ s0,
    const float* __restrict__ a_in,
    const float* __restrict__ b_in,
    float* __restrict__ log_out,   // B*8
    float* __restrict__ ns_out,    // B*8
    float* __restrict__ acc_out,   // B
    int B)
{
    const int stride = gridDim.x * blockDim.x;
    for (int i = blockIdx.x * blockDim.x + threadIdx.x; i < B; i += stride) {
        const float av = a_in[i];
        const float bv = b_in[i];
        const float ab  = av * bv;
        const float anb = av * (1.0f - bv);
        const float na  = 1.0f - av;

        // 32 B vector load of the row
        const float4* s4 = reinterpret_cast<const float4*>(s0 + (size_t)i * 8);
        const float4 lo = s4[0];
        const float4 hi = s4[1];
        const float s[8] = {lo.x, lo.y, lo.z, lo.w, hi.x, hi.y, hi.z, hi.w};

        float un[8];
        float denom = 0.0f;
#pragma unroll
        for (int n = 0; n < 8; ++n) {
            un[n] = fmaf(s[(n + 7) & 7], ab,
                    fmaf(s[(n + 6) & 7], anb, s[n] * na));
            denom += un[n];
        }

        const float inv = 1.0f / denom;

        float nsv[8], lg[8];
#pragma unroll
        for (int n = 0; n < 8; ++n) {
            float v = un[n] * inv;
            v = fminf(fmaxf(v, DFA_EPS), 1.0f - DFA_EPS);
            nsv[n] = v;
            lg[n] = __logf(v);   // v_log_f32 * ln2 — plenty for 0.215 absmax
        }

        float4* lg4 = reinterpret_cast<float4*>(log_out + (size_t)i * 8);
        lg4[0] = make_float4(lg[0], lg[1], lg[2], lg[3]);
        lg4[1] = make_float4(lg[4], lg[5], lg[6], lg[7]);

        float4* ns4 = reinterpret_cast<float4*>(ns_out + (size_t)i * 8);
        ns4[0] = make_float4(nsv[0], nsv[1], nsv[2], nsv[3]);
        ns4[1] = make_float4(nsv[4], nsv[5], nsv[6], nsv[7]);

        acc_out[i] = nsv[7];
    }
}

extern "C" void kernel_launch(void* const* d_in, const int* in_sizes, int n_in,
                              void* d_out, int out_size, void* d_ws, size_t ws_size,
                              hipStream_t stream) {
    // Inputs (setup_inputs order): log_s0 [B*8] (UNUSED), s0 [B*8], a [B], b [B]
    const float* s0 = (const float*)d_in[1];
    const float* a  = (const float*)d_in[2];
    const float* b  = (const float*)d_in[3];
    const int B = in_sizes[2];

    float* out = (float*)d_out;
    float* log_out = out;                         // [B*8]
    float* ns_out  = out + (size_t)B * 8;         // [B*8]
    float* acc_out = out + (size_t)B * 16;        // [B]

    const int block = 256;
    int grid = (B + block - 1) / block;
    if (grid > 2048) grid = 2048;                 // grid-stride the rest (G11)
    dfa_prob_kernel<<<grid, block, 0, stream>>>(s0, a, b, log_out, ns_out, acc_out, B);
}